// Round 10
// baseline (9916.231 us; speedup 1.0000x reference)
//
#include <hip/hip_runtime.h>
#include <math.h>

#define NEG_INF (-__builtin_inff())
#define POS_INF (__builtin_inff())

// ===================== DPP int max (valid f32 max for x >= 0) =====================
__device__ __forceinline__ int imax_i(int a, int b) { return a > b ? a : b; }

template<int CTRL, int RMASK>
__device__ __forceinline__ int dpp_imax_step(int y) {
  const int t = __builtin_amdgcn_update_dpp(y, y, CTRL, RMASK, 0xf, false);
  return imax_i(y, t);
}

// ============================ stage-1 fused kernel ============================
// grid = 256 blocks x 1024 threads, ~148KB LDS -> 1 block/CU.
// Blocks 0,1: FPS producers. Flush q1 rows every 256 iters; threadfence (L2
//   writeback) + release-store progress[g].
// Blocks 2..255: consumers; per query: t0 spins on progress with RELAXED
//   agent-scope loads (R9 POST-MORTEM: ACQUIRE spins emit an L2 invalidate
//   per iteration -> 1M invalidates -> 27.8 GB HBM thrash, 2.5x slowdown.
//   Relaxed agent loads bypass the XCD L2 and read the coherence point
//   (MALL) directly -> no invalidate, and they see the producer's
//   written-back q1 because the release-store orders after threadfence).
//   q coords are read via relaxed agent atomic loads for the same reason.
// DEADLOCK-FREE: producers never wait on consumers.
struct ProdS {
  unsigned long long slot[4];
  float sxyz[3 * 8192];      // interleaved coords, ORIGINAL-index order
  int sorder[8192];
  int hist[4096];            // reused as winner list after setup
  int scanbuf[1024];
};
struct ConsS {
  unsigned long long keys[1024];
  float sW2[64 * 64];
  float sW3[64 * 128];
  float sW1[3 * 64];
  float sb1[64], sb2[64], sb3[128];
  float h1[64][65];
  float h2b[64][65];
  float featT[3][64];
  float qxyz[3];
  int snb[64];
  int s_cnt;
};
constexpr size_t SM1 = sizeof(ProdS) > sizeof(ConsS) ? sizeof(ProdS) : sizeof(ConsS);

__global__ __launch_bounds__(1024, 4)
void stage1_kernel(const float* __restrict__ pos,
                   float* __restrict__ q1,
                   float* __restrict__ x1,
                   unsigned int* __restrict__ progress,
                   const float* __restrict__ W1, const float* __restrict__ b1,
                   const float* __restrict__ W2, const float* __restrict__ b2,
                   const float* __restrict__ W3, const float* __restrict__ b3)
{
  constexpr int N = 8192, PPT = 8, S = 4096, NT = 1024;
  constexpr int CELLS = 4096, CPT = CELLS / NT;
  __shared__ __align__(16) char smraw[SM1];
  const int bid = blockIdx.x;
  const int t = threadIdx.x;

  if (bid < 2) {
    // ======================= PRODUCER: FPS =======================
    ProdS& P = *reinterpret_cast<ProdS*>(smraw);
    const float* pb = pos + (size_t)bid * N * 3;
    float* qb = q1 + (size_t)bid * S * 3;
    int* const swin = P.hist;

    for (int i = t; i < CELLS; i += NT) P.hist[i] = 0;
    if (t < 4) P.slot[t] = 0;
    __syncthreads();
    for (int i = t; i < N; i += NT) {
      const float x = pb[3*i+0], y = pb[3*i+1], z = pb[3*i+2];
      P.sxyz[3*i+0] = x; P.sxyz[3*i+1] = y; P.sxyz[3*i+2] = z;
      int cx = (int)(x * 16.f); cx = cx < 0 ? 0 : (cx > 15 ? 15 : cx);
      int cy = (int)(y * 16.f); cy = cy < 0 ? 0 : (cy > 15 ? 15 : cy);
      int cz = (int)(z * 16.f); cz = cz < 0 ? 0 : (cz > 15 ? 15 : cz);
      int m = 0;
#pragma unroll
      for (int k = 0; k < 4; ++k)
        m |= (((cx >> k) & 1) << (3*k+2)) | (((cy >> k) & 1) << (3*k+1)) | (((cz >> k) & 1) << (3*k));
      atomicAdd(&P.hist[m], 1);
    }
    __syncthreads();
    int loc[CPT]; int run = 0;
#pragma unroll
    for (int j = 0; j < CPT; ++j) { loc[j] = run; run += P.hist[t*CPT + j]; }
    P.scanbuf[t] = run;
    __syncthreads();
    for (int off = 1; off < NT; off <<= 1) {
      const int o = (t >= off) ? P.scanbuf[t - off] : 0;
      __syncthreads();
      P.scanbuf[t] += o;
      __syncthreads();
    }
    const int base = P.scanbuf[t] - run;
#pragma unroll
    for (int j = 0; j < CPT; ++j) P.hist[t*CPT + j] = base + loc[j];
    __syncthreads();
    for (int i = t; i < N; i += NT) {
      const float x = P.sxyz[3*i+0], y = P.sxyz[3*i+1], z = P.sxyz[3*i+2];
      int cx = (int)(x * 16.f); cx = cx < 0 ? 0 : (cx > 15 ? 15 : cx);
      int cy = (int)(y * 16.f); cy = cy < 0 ? 0 : (cy > 15 ? 15 : cy);
      int cz = (int)(z * 16.f); cz = cz < 0 ? 0 : (cz > 15 ? 15 : cz);
      int m = 0;
#pragma unroll
      for (int k = 0; k < 4; ++k)
        m |= (((cx >> k) & 1) << (3*k+2)) | (((cy >> k) & 1) << (3*k+1)) | (((cz >> k) & 1) << (3*k));
      const int sl = atomicAdd(&P.hist[m], 1);
      P.sorder[sl] = i;
    }
    __syncthreads();
    float px[PPT], py[PPT], pz[PPT], d[PPT];
    int og[PPT];
    float bxmin = POS_INF, bxmax = NEG_INF, bymin = POS_INF, bymax = NEG_INF,
          bzmin = POS_INF, bzmax = NEG_INF;
#pragma unroll
    for (int j = 0; j < PPT; ++j) {
      const int o = P.sorder[t*PPT + j];
      og[j] = o;
      const float x = P.sxyz[3*o+0], y = P.sxyz[3*o+1], z = P.sxyz[3*o+2];
      px[j] = x; py[j] = y; pz[j] = z;
      bxmin = fminf(bxmin, x); bxmax = fmaxf(bxmax, x);
      bymin = fminf(bymin, y); bymax = fmaxf(bymax, y);
      bzmin = fminf(bzmin, z); bzmax = fmaxf(bzmax, z);
      d[j] = POS_INF;
    }
    __syncthreads();

    const int lane = t & 63;
    float cval = POS_INF;
    int corig = 0x7fffffff;
    int wmvb = 0;
    int wwo = 0x7fffffff;
    int worig = 0;
    int p = 0;
    int pend = 0;

    for (int it = 0; it < S; ++it) {
      // flush previous 256-row chunk (entries all barrier-visible)
      if (it && (it & 255) == 0) {
        for (int i = it - 256 + t; i < it; i += NT) {
          const int o = swin[i];
          qb[3*i+0] = P.sxyz[3*o+0]; qb[3*i+1] = P.sxyz[3*o+1]; qb[3*i+2] = P.sxyz[3*o+2];
        }
        pend = it;
      }
      if (t == 0) swin[it] = worig;
      const float lx = P.sxyz[3*worig+0], ly = P.sxyz[3*worig+1], lz = P.sxyz[3*worig+2];

      const float ddx = fmaxf(0.f, fmaxf(bxmin - lx, lx - bxmax));
      const float ddy = fmaxf(0.f, fmaxf(bymin - ly, ly - bymax));
      const float ddz = fmaxf(0.f, fmaxf(bzmin - lz, lz - bzmax));
      const float mind2 = ddx*ddx + ddy*ddy + ddz*ddz;
      const bool rec = !(mind2 * 0.99999f >= cval);

      if (rec) {
        float bv = -1.f; int bo = 0x7fffffff;
#pragma unroll
        for (int j = 0; j < PPT; ++j) {
          const float dx = __fsub_rn(px[j], lx);
          const float dy = __fsub_rn(py[j], ly);
          const float dz = __fsub_rn(pz[j], lz);
          const float nd = __fadd_rn(__fadd_rn(__fmul_rn(dx, dx), __fmul_rn(dy, dy)),
                                     __fmul_rn(dz, dz));
          const float dn = __builtin_fminf(d[j], nd);
          d[j] = dn;
          if (dn > bv || (dn == bv && og[j] < bo)) { bv = dn; bo = og[j]; }
        }
        cval = bv; corig = bo;
      }

      if (__ballot(rec) != 0ULL) {
        const int x = __float_as_int(cval);
        int y = x;
        y = dpp_imax_step<0x111, 0xf>(y);
        y = dpp_imax_step<0x112, 0xf>(y);
        y = dpp_imax_step<0x114, 0xf>(y);
        y = dpp_imax_step<0x118, 0xf>(y);
        y = dpp_imax_step<0x142, 0xa>(y);
        y = dpp_imax_step<0x143, 0xc>(y);
        wmvb = __builtin_amdgcn_readlane(y, 63);
        unsigned long long tie = __ballot(__float_as_int(cval) == wmvb);
        int wo = 0x7fffffff;
        while (tie) {
          const int l = __builtin_ctzll(tie);
          const int o = __builtin_amdgcn_readlane(corig, l);
          wo = wo < o ? wo : o;
          tie &= tie - 1;
        }
        wwo = wo;
      }

      if (lane == 0)
        atomicMax(&P.slot[p], ((unsigned long long)(unsigned)wmvb << 32) |
                              (unsigned)~(unsigned)wwo);
      if (t == 0) P.slot[(p + 1) & 3] = 0;
      __syncthreads();   // drains each wave's flush stores too (vmcnt(0))
      if (pend && t == 0) {
        __threadfence();
        __hip_atomic_store(&progress[bid], (unsigned)pend,
                           __ATOMIC_RELEASE, __HIP_MEMORY_SCOPE_AGENT);
      }
      pend = 0;
      const unsigned long long wm = P.slot[p];
      worig = (int)(~(unsigned)(wm & 0xffffffffULL));
      p = (p + 1) & 3;
    }

    __syncthreads();
    for (int i = S - 256 + t; i < S; i += NT) {
      const int o = swin[i];
      qb[3*i+0] = P.sxyz[3*o+0]; qb[3*i+1] = P.sxyz[3*o+1]; qb[3*i+2] = P.sxyz[3*o+2];
    }
    __syncthreads();   // vmcnt(0) drain of final flush
    if (t == 0) {
      __threadfence();
      __hip_atomic_store(&progress[bid], (unsigned)S,
                         __ATOMIC_RELEASE, __HIP_MEMORY_SCOPE_AGENT);
    }
    return;
  }

  // ======================= CONSUMER: fused knn1 + mlp1 =======================
  ConsS& C = *reinterpret_cast<ConsS*>(smraw);
  const float R1SQ = (float)(0.2 * 0.2);

  // stage SA1 weights once per block
  for (int i = t; i < 192; i += 1024) C.sW1[i] = W1[i];
  if (t < 64) { C.sb1[t] = b1[t]; C.sb2[t] = b2[t]; }
  for (int i = t; i < 4096; i += 1024) C.sW2[i] = W2[i];
  for (int i = t; i < 8192; i += 1024) C.sW3[i] = W3[i];
  if (t < 128) C.sb3[t] = b3[t];
  __syncthreads();

  const int e = t & 63, cg = t >> 6;

  for (int qi = bid - 2; qi < 8192; qi += 254) {
    const int g = qi >> 12;
    const int s = qi & 4095;
    // gate on producer progress with RELAXED agent loads (MALL reads, no
    // cache invalidation); producer's threadfence+release makes q1 visible
    // to the relaxed agent-scope coordinate loads below.
    if (t == 0) {
      while (__hip_atomic_load(&progress[g], __ATOMIC_RELAXED,
                               __HIP_MEMORY_SCOPE_AGENT) <= (unsigned)s)
        __builtin_amdgcn_s_sleep(32);
#pragma unroll
      for (int c = 0; c < 3; ++c) {
        const unsigned u = __hip_atomic_load(
            (const unsigned*)(q1 + (size_t)3*qi + c),
            __ATOMIC_RELAXED, __HIP_MEMORY_SCOPE_AGENT);
        C.qxyz[c] = __uint_as_float(u);
      }
      C.s_cnt = 0;
    }
    __syncthreads();
    const float qx = C.qxyz[0], qy = C.qxyz[1], qz = C.qxyz[2];
    const float* cb = pos + (size_t)g * 8192 * 3;

    // ---- radius compaction (exact ops) ----
    for (int i = t; i < 8192; i += 1024) {
      const float dx = __fsub_rn(cb[3*i+0], qx);
      const float dy = __fsub_rn(cb[3*i+1], qy);
      const float dz = __fsub_rn(cb[3*i+2], qz);
      const float d2 = __fadd_rn(__fadd_rn(__fmul_rn(dx, dx), __fmul_rn(dy, dy)),
                                 __fmul_rn(dz, dz));
      if (d2 <= R1SQ) {
        const int pp = atomicAdd(&C.s_cnt, 1);
        if (pp < 1024)
          C.keys[pp] = ((unsigned long long)__float_as_uint(d2) << 32) | (unsigned)i;
      }
    }
    __syncthreads();
    const int M = min(C.s_cnt, 1024);
    const int cnt = min(M, 64);
    if (M > 64) {
      int P2 = 128; while (P2 < M) P2 <<= 1;
      for (int i = M + t; i < P2; i += 1024) C.keys[i] = ~0ULL;
      __syncthreads();
      for (int k = 2; k <= P2; k <<= 1) {
        for (int j = k >> 1; j > 0; j >>= 1) {
          if (t < P2) {
            const int l = t ^ j;
            if (l > t) {
              const unsigned long long a = C.keys[t], c = C.keys[l];
              const bool up = ((t & k) == 0);
              if ((a > c) == up) { C.keys[t] = c; C.keys[l] = a; }
            }
          }
          __syncthreads();
        }
      }
    }
    if (t < 64) C.snb[t] = (t < cnt) ? (int)(C.keys[t] & 0xffffffffu) : 0;
    __syncthreads();

    // ---- SA1 edge MLP (identical arithmetic to prior mlp1) ----
    if (t < 64) {
      float r0 = 0.f, r1 = 0.f, r2v = 0.f;
      if (t < cnt) {
        const int nb = C.snb[t];
        r0 = cb[3*nb+0] - qx;
        r1 = cb[3*nb+1] - qy;
        r2v = cb[3*nb+2] - qz;
      }
      C.featT[0][t] = r0; C.featT[1][t] = r1; C.featT[2][t] = r2v;
    }
    __syncthreads();
    { // layer1: 64 cols / 16 groups = 4 cols
      const int c0 = cg * 4;
      const float a0 = C.featT[0][e], a1 = C.featT[1][e], a2 = C.featT[2][e];
#pragma unroll
      for (int i = 0; i < 4; ++i) {
        float v = C.sb1[c0+i];
        v = fmaf(a0, C.sW1[0*64 + c0+i], v);
        v = fmaf(a1, C.sW1[1*64 + c0+i], v);
        v = fmaf(a2, C.sW1[2*64 + c0+i], v);
        C.h1[e][c0+i] = fmaxf(v, 0.f);
      }
    }
    __syncthreads();
    { // layer2: 64 cols / 16 groups = 4 cols
      const int c0 = cg * 4;
      float acc[4];
#pragma unroll
      for (int i = 0; i < 4; ++i) acc[i] = C.sb2[c0+i];
      for (int k = 0; k < 64; ++k) {
        const float a = C.h1[e][k];
        const float4 w = *reinterpret_cast<const float4*>(&C.sW2[k*64 + c0]);
        acc[0] = fmaf(a, w.x, acc[0]);
        acc[1] = fmaf(a, w.y, acc[1]);
        acc[2] = fmaf(a, w.z, acc[2]);
        acc[3] = fmaf(a, w.w, acc[3]);
      }
#pragma unroll
      for (int i = 0; i < 4; ++i) C.h2b[e][c0+i] = fmaxf(acc[i], 0.f);
    }
    __syncthreads();
    float acc3[8];
    const int c0h = cg * 8;
    { // layer3: 128 cols / 16 groups = 8 cols (no relu)
#pragma unroll
      for (int i = 0; i < 8; ++i) acc3[i] = C.sb3[c0h+i];
      for (int k = 0; k < 64; ++k) {
        const float a = C.h2b[e][k];
        const float4* wp = reinterpret_cast<const float4*>(&C.sW3[k*128 + c0h]);
        const float4 w0 = wp[0], w1 = wp[1];
        acc3[0] = fmaf(a, w0.x, acc3[0]);
        acc3[1] = fmaf(a, w0.y, acc3[1]);
        acc3[2] = fmaf(a, w0.z, acc3[2]);
        acc3[3] = fmaf(a, w0.w, acc3[3]);
        acc3[4] = fmaf(a, w1.x, acc3[4]);
        acc3[5] = fmaf(a, w1.y, acc3[5]);
        acc3[6] = fmaf(a, w1.z, acc3[6]);
        acc3[7] = fmaf(a, w1.w, acc3[7]);
      }
    }
    __syncthreads();   // all h1/h2b reads done before restaging
    {
      const bool valid = (e < cnt);
#pragma unroll
      for (int i = 0; i < 8; ++i) {
        const float v = valid ? acc3[i] : NEG_INF;
        const int c = c0h + i;
        if (c < 64) C.h1[e][c] = v; else C.h2b[e][c-64] = v;
      }
    }
    __syncthreads();
    if (t < 128) {
      float m = NEG_INF;
      if (t < 64) {
        for (int ee = 0; ee < 64; ++ee) m = fmaxf(m, C.h1[ee][t]);
      } else {
        for (int ee = 0; ee < 64; ++ee) m = fmaxf(m, C.h2b[ee][t-64]);
      }
      x1[(size_t)qi*128 + t] = m;
    }
    __syncthreads();   // before next query reuses LDS
  }
}

// ============================ FPS (standalone, for fps2) ============================
template<int N, int PPT, int S, int NT>
__global__ __launch_bounds__(NT) void fpsp_kernel(const float* __restrict__ pos,
                                                  float* __restrict__ q_out)
{
  constexpr int CELLS = 4096;
  constexpr int CPT = CELLS / NT;
  static_assert(N == NT * PPT, "chunking");
  static_assert(S <= CELLS, "winner list fits in hist");

  const int b = blockIdx.x;
  const int t = threadIdx.x;
  pos += (size_t)b * N * 3;
  q_out += (size_t)b * S * 3;

  __shared__ float sxyz[3 * N];
  __shared__ int sorder[N];
  __shared__ int hist[CELLS];
  __shared__ int scanbuf[NT];
  __shared__ unsigned long long slot[4];

  int* const swin = hist;

  for (int i = t; i < CELLS; i += NT) hist[i] = 0;
  if (t < 4) slot[t] = 0;
  __syncthreads();
  for (int i = t; i < N; i += NT) {
    const float x = pos[3*i+0], y = pos[3*i+1], z = pos[3*i+2];
    sxyz[3*i+0] = x; sxyz[3*i+1] = y; sxyz[3*i+2] = z;
    int cx = (int)(x * 16.f); cx = cx < 0 ? 0 : (cx > 15 ? 15 : cx);
    int cy = (int)(y * 16.f); cy = cy < 0 ? 0 : (cy > 15 ? 15 : cy);
    int cz = (int)(z * 16.f); cz = cz < 0 ? 0 : (cz > 15 ? 15 : cz);
    int m = 0;
#pragma unroll
    for (int k = 0; k < 4; ++k)
      m |= (((cx >> k) & 1) << (3*k+2)) | (((cy >> k) & 1) << (3*k+1)) | (((cz >> k) & 1) << (3*k));
    atomicAdd(&hist[m], 1);
  }
  __syncthreads();
  int loc[CPT]; int run = 0;
#pragma unroll
  for (int j = 0; j < CPT; ++j) { loc[j] = run; run += hist[t*CPT + j]; }
  scanbuf[t] = run;
  __syncthreads();
  for (int off = 1; off < NT; off <<= 1) {
    const int o = (t >= off) ? scanbuf[t - off] : 0;
    __syncthreads();
    scanbuf[t] += o;
    __syncthreads();
  }
  const int base = scanbuf[t] - run;
#pragma unroll
  for (int j = 0; j < CPT; ++j) hist[t*CPT + j] = base + loc[j];
  __syncthreads();
  for (int i = t; i < N; i += NT) {
    const float x = sxyz[3*i+0], y = sxyz[3*i+1], z = sxyz[3*i+2];
    int cx = (int)(x * 16.f); cx = cx < 0 ? 0 : (cx > 15 ? 15 : cx);
    int cy = (int)(y * 16.f); cy = cy < 0 ? 0 : (cy > 15 ? 15 : cy);
    int cz = (int)(z * 16.f); cz = cz < 0 ? 0 : (cz > 15 ? 15 : cz);
    int m = 0;
#pragma unroll
    for (int k = 0; k < 4; ++k)
      m |= (((cx >> k) & 1) << (3*k+2)) | (((cy >> k) & 1) << (3*k+1)) | (((cz >> k) & 1) << (3*k));
    const int sl = atomicAdd(&hist[m], 1);
    sorder[sl] = i;
  }
  __syncthreads();
  float px[PPT], py[PPT], pz[PPT], d[PPT];
  int og[PPT];
  float bxmin = POS_INF, bxmax = NEG_INF, bymin = POS_INF, bymax = NEG_INF,
        bzmin = POS_INF, bzmax = NEG_INF;
#pragma unroll
  for (int j = 0; j < PPT; ++j) {
    const int o = sorder[t*PPT + j];
    og[j] = o;
    const float x = sxyz[3*o+0], y = sxyz[3*o+1], z = sxyz[3*o+2];
    px[j] = x; py[j] = y; pz[j] = z;
    bxmin = fminf(bxmin, x); bxmax = fmaxf(bxmax, x);
    bymin = fminf(bymin, y); bymax = fmaxf(bymax, y);
    bzmin = fminf(bzmin, z); bzmax = fmaxf(bzmax, z);
    d[j] = POS_INF;
  }
  __syncthreads();

  const int lane = t & 63;
  float cval = POS_INF;
  int corig = 0x7fffffff;
  int wmvb = 0;
  int wwo = 0x7fffffff;
  int worig = 0;
  int p = 0;

  for (int it = 0; it < S; ++it) {
    if (t == 0) swin[it] = worig;
    const float lx = sxyz[3*worig+0], ly = sxyz[3*worig+1], lz = sxyz[3*worig+2];

    const float ddx = fmaxf(0.f, fmaxf(bxmin - lx, lx - bxmax));
    const float ddy = fmaxf(0.f, fmaxf(bymin - ly, ly - bymax));
    const float ddz = fmaxf(0.f, fmaxf(bzmin - lz, lz - bzmax));
    const float mind2 = ddx*ddx + ddy*ddy + ddz*ddz;
    const bool rec = !(mind2 * 0.99999f >= cval);

    if (rec) {
      float bv = -1.f; int bo = 0x7fffffff;
#pragma unroll
      for (int j = 0; j < PPT; ++j) {
        const float dx = __fsub_rn(px[j], lx);
        const float dy = __fsub_rn(py[j], ly);
        const float dz = __fsub_rn(pz[j], lz);
        const float nd = __fadd_rn(__fadd_rn(__fmul_rn(dx, dx), __fmul_rn(dy, dy)),
                                   __fmul_rn(dz, dz));
        const float dn = __builtin_fminf(d[j], nd);
        d[j] = dn;
        if (dn > bv || (dn == bv && og[j] < bo)) { bv = dn; bo = og[j]; }
      }
      cval = bv; corig = bo;
    }

    if (__ballot(rec) != 0ULL) {
      const int x = __float_as_int(cval);
      int y = x;
      y = dpp_imax_step<0x111, 0xf>(y);
      y = dpp_imax_step<0x112, 0xf>(y);
      y = dpp_imax_step<0x114, 0xf>(y);
      y = dpp_imax_step<0x118, 0xf>(y);
      y = dpp_imax_step<0x142, 0xa>(y);
      y = dpp_imax_step<0x143, 0xc>(y);
      wmvb = __builtin_amdgcn_readlane(y, 63);
      unsigned long long tie = __ballot(__float_as_int(cval) == wmvb);
      int wo = 0x7fffffff;
      while (tie) {
        const int l = __builtin_ctzll(tie);
        const int o = __builtin_amdgcn_readlane(corig, l);
        wo = wo < o ? wo : o;
        tie &= tie - 1;
      }
      wwo = wo;
    }

    if (lane == 0)
      atomicMax(&slot[p], ((unsigned long long)(unsigned)wmvb << 32) |
                          (unsigned)~(unsigned)wwo);
    if (t == 0) slot[(p + 1) & 3] = 0;
    __syncthreads();
    const unsigned long long wm = slot[p];
    worig = (int)(~(unsigned)(wm & 0xffffffffULL));
    p = (p + 1) & 3;
  }

  __syncthreads();
  for (int s = t; s < S; s += NT) {
    const int o = swin[s];
    q_out[3*s+0] = sxyz[3*o+0]; q_out[3*s+1] = sxyz[3*o+1]; q_out[3*s+2] = sxyz[3*o+2];
  }
}

// ============================ radius-KNN (stage 2) ============================
#define KNN_CAP 2048

__global__ __launch_bounds__(256) void knn_kernel(const float* __restrict__ cand,
                                                  const float* __restrict__ qpos,
                                                  int nq_per_graph, int n_cand, float r2,
                                                  int* __restrict__ nbr_out,
                                                  int* __restrict__ cnt_out)
{
  const int qi = blockIdx.x;
  const int t = threadIdx.x;
  const int b = qi / nq_per_graph;
  const float* cb = cand + (size_t)b * n_cand * 3;
  const float qx = qpos[3*qi+0], qy = qpos[3*qi+1], qz = qpos[3*qi+2];

  __shared__ unsigned long long keys[KNN_CAP];
  __shared__ int s_cnt;
  if (t == 0) s_cnt = 0;
  __syncthreads();

  for (int i = t; i < n_cand; i += 256) {
    const float dx = __fsub_rn(cb[3*i+0], qx);
    const float dy = __fsub_rn(cb[3*i+1], qy);
    const float dz = __fsub_rn(cb[3*i+2], qz);
    const float d2 = __fadd_rn(__fadd_rn(__fmul_rn(dx, dx), __fmul_rn(dy, dy)),
                               __fmul_rn(dz, dz));
    if (d2 <= r2) {
      const int p = atomicAdd(&s_cnt, 1);
      if (p < KNN_CAP) keys[p] = ((unsigned long long)__float_as_uint(d2) << 32) | (unsigned)i;
    }
  }
  __syncthreads();
  const int M = min(s_cnt, KNN_CAP);
  const int out_n = min(M, 64);
  if (M > 64) {
    int P = 128; while (P < M) P <<= 1;
    for (int i = M + t; i < P; i += 256) keys[i] = ~0ULL;
    __syncthreads();
    for (int k = 2; k <= P; k <<= 1) {
      for (int j = k >> 1; j > 0; j >>= 1) {
        for (int i = t; i < P; i += 256) {
          const int l = i ^ j;
          if (l > i) {
            const unsigned long long a = keys[i], c = keys[l];
            const bool up = ((i & k) == 0);
            if ((a > c) == up) { keys[i] = c; keys[l] = a; }
          }
        }
        __syncthreads();
      }
    }
  }
  if (t < 64) nbr_out[(size_t)qi*64 + t] = (t < out_n) ? (int)(keys[t] & 0xffffffffu) : -1;
  if (t == 0) cnt_out[qi] = out_n;
}

// ============================ SA2 edge MLP (131->128->128->256) + max ============================
__global__ __launch_bounds__(256) void mlp2_kernel(const float* __restrict__ q1,
                                                   const float* __restrict__ x1,
                                                   const float* __restrict__ q2,
                                                   const int* __restrict__ nbr,
                                                   const int* __restrict__ cnt_,
                                                   const float* __restrict__ W1, const float* __restrict__ b1,
                                                   const float* __restrict__ W2, const float* __restrict__ b2,
                                                   const float* __restrict__ W3, const float* __restrict__ b3,
                                                   float* __restrict__ x2)
{
  const int qi = blockIdx.x;
  const int t = threadIdx.x;
  const int bg = qi >> 10;                       // 1024 queries per graph
  const float* cb = q1 + (size_t)bg * 4096 * 3;
  const float* xb = x1 + (size_t)bg * 4096 * 128;

  __shared__ float sW[131*128];
  __shared__ float sb[256];
  __shared__ float featT[131][64];
  __shared__ float hbuf[64][129];
  __shared__ int snb[64];

  const int cnt = cnt_[qi];
  const float qx = q2[3*qi+0], qy = q2[3*qi+1], qz = q2[3*qi+2];

  if (t < 64) {
    const int nb = (t < cnt) ? nbr[(size_t)qi*64 + t] : 0;
    snb[t] = nb;
    float r0 = 0.f, r1 = 0.f, r2v = 0.f;
    if (t < cnt) {
      r0 = cb[3*nb+0] - qx;
      r1 = cb[3*nb+1] - qy;
      r2v = cb[3*nb+2] - qz;
    }
    featT[128][t] = r0; featT[129][t] = r1; featT[130][t] = r2v;
  }
  for (int i = t; i < 131*128; i += 256) sW[i] = W1[i];
  if (t < 128) sb[t] = b1[t];
  __syncthreads();
  for (int idx = t; idx < 64*128; idx += 256) {
    const int e = idx >> 7, k = idx & 127;
    featT[k][e] = (e < cnt) ? xb[(size_t)snb[e]*128 + k] : 0.f;
  }
  __syncthreads();

  const int e = t & 63, cg = t >> 6, c0 = cg * 32;
  float acc[32];
  { // layer1: 131 -> 128
#pragma unroll
    for (int i = 0; i < 32; ++i) acc[i] = sb[c0+i];
    for (int k = 0; k < 131; ++k) {
      const float a = featT[k][e];
      const float4* wp = reinterpret_cast<const float4*>(&sW[k*128 + c0]);
#pragma unroll
      for (int i = 0; i < 8; ++i) {
        const float4 w = wp[i];
        acc[4*i+0] = fmaf(a, w.x, acc[4*i+0]);
        acc[4*i+1] = fmaf(a, w.y, acc[4*i+1]);
        acc[4*i+2] = fmaf(a, w.z, acc[4*i+2]);
        acc[4*i+3] = fmaf(a, w.w, acc[4*i+3]);
      }
    }
#pragma unroll
    for (int i = 0; i < 32; ++i) hbuf[e][c0+i] = fmaxf(acc[i], 0.f);
  }
  __syncthreads();
  for (int i = t; i < 128*128; i += 256) sW[i] = W2[i];
  if (t < 128) sb[t] = b2[t];
  __syncthreads();
  { // layer2
#pragma unroll
    for (int i = 0; i < 32; ++i) acc[i] = sb[c0+i];
    for (int k = 0; k < 128; ++k) {
      const float a = hbuf[e][k];
      const float4* wp = reinterpret_cast<const float4*>(&sW[k*128 + c0]);
#pragma unroll
      for (int i = 0; i < 8; ++i) {
        const float4 w = wp[i];
        acc[4*i+0] = fmaf(a, w.x, acc[4*i+0]);
        acc[4*i+1] = fmaf(a, w.y, acc[4*i+1]);
        acc[4*i+2] = fmaf(a, w.z, acc[4*i+2]);
        acc[4*i+3] = fmaf(a, w.w, acc[4*i+3]);
      }
    }
  }
  __syncthreads();
#pragma unroll
  for (int i = 0; i < 32; ++i) featT[c0+i][e] = fmaxf(acc[i], 0.f);
  __syncthreads();
  for (int hh = 0; hh < 2; ++hh) {
    for (int i = t; i < 128*128; i += 256) {
      const int k = i >> 7, c = i & 127;
      sW[i] = W3[k*256 + hh*128 + c];
    }
    if (t < 128) sb[t] = b3[hh*128 + t];
    __syncthreads();
#pragma unroll
    for (int i = 0; i < 32; ++i) acc[i] = sb[c0+i];
    for (int k = 0; k < 128; ++k) {
      const float a = featT[k][e];
      const float4* wp = reinterpret_cast<const float4*>(&sW[k*128 + c0]);
#pragma unroll
      for (int i = 0; i < 8; ++i) {
        const float4 w = wp[i];
        acc[4*i+0] = fmaf(a, w.x, acc[4*i+0]);
        acc[4*i+1] = fmaf(a, w.y, acc[4*i+1]);
        acc[4*i+2] = fmaf(a, w.z, acc[4*i+2]);
        acc[4*i+3] = fmaf(a, w.w, acc[4*i+3]);
      }
    }
    const bool valid = (e < cnt);
#pragma unroll
    for (int i = 0; i < 32; ++i) hbuf[e][c0+i] = valid ? acc[i] : NEG_INF;
    __syncthreads();
    if (t < 128) {
      float m = NEG_INF;
      for (int ee = 0; ee < 64; ++ee) m = fmaxf(m, hbuf[ee][t]);
      x2[(size_t)qi*256 + hh*128 + t] = m;
    }
    __syncthreads();
  }
}

// ============================ head MLP (256->256->128->1, sigmoid) ============================
__global__ __launch_bounds__(256) void head_kernel(const float* __restrict__ x2,
                                                   const float* __restrict__ W1, const float* __restrict__ b1,
                                                   const float* __restrict__ W2, const float* __restrict__ b2,
                                                   const float* __restrict__ W3, const float* __restrict__ b3,
                                                   float* __restrict__ out)
{
  const int pt = blockIdx.x;
  const int t = threadIdx.x;
  __shared__ float sx[256];
  __shared__ float sh1[256];
  __shared__ float sh2[128];
  __shared__ float red[128];

  sx[t] = x2[(size_t)pt*256 + t];
  __syncthreads();
  float a1 = b1[t];
  for (int k = 0; k < 256; ++k) a1 = fmaf(sx[k], W1[k*256 + t], a1);
  sh1[t] = fmaxf(a1, 0.f);
  __syncthreads();
  if (t < 128) {
    float a2 = b2[t];
    for (int k = 0; k < 256; ++k) a2 = fmaf(sh1[k], W2[k*128 + t], a2);
    sh2[t] = fmaxf(a2, 0.f);
  }
  __syncthreads();
  if (t < 128) red[t] = sh2[t] * W3[t];
  __syncthreads();
  for (int o = 64; o > 0; o >>= 1) {
    if (t < o) red[t] += red[t + o];
    __syncthreads();
  }
  if (t == 0) {
    const float v = red[0] + b3[0];
    out[pt] = 1.f / (1.f + expf(-v));
  }
}

// ============================ launcher ============================
extern "C" void kernel_launch(void* const* d_in, const int* in_sizes, int n_in,
                              void* d_out, int out_size, void* d_ws, size_t ws_size,
                              hipStream_t stream)
{
  (void)in_sizes; (void)n_in; (void)out_size; (void)ws_size;
  const float* pos  = (const float*)d_in[0];
  const float* s1W1 = (const float*)d_in[2];  const float* s1b1 = (const float*)d_in[3];
  const float* s1W2 = (const float*)d_in[4];  const float* s1b2 = (const float*)d_in[5];
  const float* s1W3 = (const float*)d_in[6];  const float* s1b3 = (const float*)d_in[7];
  const float* s2W1 = (const float*)d_in[8];  const float* s2b1 = (const float*)d_in[9];
  const float* s2W2 = (const float*)d_in[10]; const float* s2b2 = (const float*)d_in[11];
  const float* s2W3 = (const float*)d_in[12]; const float* s2b3 = (const float*)d_in[13];
  const float* l1W  = (const float*)d_in[14]; const float* l1b  = (const float*)d_in[15];
  const float* l2W  = (const float*)d_in[16]; const float* l2b  = (const float*)d_in[17];
  const float* l3W  = (const float*)d_in[18]; const float* l3b  = (const float*)d_in[19];
  float* out = (float*)d_out;

  char* w = (char*)d_ws;
  size_t off = 0;
  auto alloc = [&](size_t bytes) -> void* {
    void* p = w + off;
    off += (bytes + 255) & ~(size_t)255;
    return p;
  };
  float* q1   = (float*)alloc((size_t)2*4096*3*4);
  float* q2   = (float*)alloc((size_t)2*1024*3*4);
  float* x1   = (float*)alloc((size_t)8192*128*4);
  float* x2   = (float*)alloc((size_t)2048*256*4);
  int*   nbr2 = (int*)alloc((size_t)2048*64*4);
  int*   cnt2 = (int*)alloc((size_t)2048*4);
  unsigned int* progress = (unsigned int*)alloc(2*sizeof(unsigned int));

  const float R2SQ = (float)(0.4 * 0.4);

  // reset producer progress before the fused dispatch (graph-capturable)
  hipMemsetAsync(progress, 0, 2*sizeof(unsigned int), stream);

  // stage 1: fps1 producers + fused knn1/mlp1 consumers, overlapped
  stage1_kernel<<<dim3(256), dim3(1024), 0, stream>>>(pos, q1, x1, progress,
                                                      s1W1, s1b1, s1W2, s1b2, s1W3, s1b3);
  // stage 2 (serial this round)
  fpsp_kernel<4096, 4, 1024, 1024><<<dim3(2), dim3(1024), 0, stream>>>(q1, q2);
  knn_kernel<<<dim3(2048), dim3(256), 0, stream>>>(q1, q2, 1024, 4096, R2SQ, nbr2, cnt2);
  mlp2_kernel<<<dim3(2048), dim3(256), 0, stream>>>(q1, x1, q2, nbr2, cnt2,
                                                    s2W1, s2b1, s2W2, s2b2, s2W3, s2b3, x2);
  head_kernel<<<dim3(2048), dim3(256), 0, stream>>>(x2, l1W, l1b, l2W, l2b, l3W, l3b, out);
}

// Round 11
// 4793.668 us; speedup vs baseline: 2.0686x; 2.0686x over previous
//
#include <hip/hip_runtime.h>
#include <math.h>

#define NEG_INF (-__builtin_inff())
#define POS_INF (__builtin_inff())

// ===================== DPP int max (valid f32 max for x >= 0) =====================
__device__ __forceinline__ int imax_i(int a, int b) { return a > b ? a : b; }

template<int CTRL, int RMASK>
__device__ __forceinline__ int dpp_imax_step(int y) {
  const int t = __builtin_amdgcn_update_dpp(y, y, CTRL, RMASK, 0xf, false);
  return imax_i(y, t);
}

// ============================ FPS (pruned, exact) ============================
// Bit-exact replica of reference lax.scan FPS (R6-measured-best structure):
//   Morton counting sort; per-lane bbox skip; cached wave-reduce; per-wave LDS
//   u64 atomicMax into 4-rotating slots before the barrier; one broadcast slot
//   read after; winner list in LDS, q_out written once at the end.
template<int N, int PPT, int S, int NT>
__global__ __launch_bounds__(NT) void fpsp_kernel(const float* __restrict__ pos,
                                                  float* __restrict__ q_out)
{
  constexpr int CELLS = 4096;
  constexpr int CPT = CELLS / NT;
  static_assert(N == NT * PPT, "chunking");
  static_assert(S <= CELLS, "winner list fits in hist");

  const int b = blockIdx.x;
  const int t = threadIdx.x;
  pos += (size_t)b * N * 3;
  q_out += (size_t)b * S * 3;

  __shared__ float sxyz[3 * N];              // interleaved, ORIGINAL-index order
  __shared__ int sorder[N];
  __shared__ int hist[CELLS];                // reused as winner list after setup
  __shared__ int scanbuf[NT];
  __shared__ unsigned long long slot[4];

  int* const swin = hist;

  for (int i = t; i < CELLS; i += NT) hist[i] = 0;
  if (t < 4) slot[t] = 0;
  __syncthreads();
  for (int i = t; i < N; i += NT) {
    const float x = pos[3*i+0], y = pos[3*i+1], z = pos[3*i+2];
    sxyz[3*i+0] = x; sxyz[3*i+1] = y; sxyz[3*i+2] = z;
    int cx = (int)(x * 16.f); cx = cx < 0 ? 0 : (cx > 15 ? 15 : cx);
    int cy = (int)(y * 16.f); cy = cy < 0 ? 0 : (cy > 15 ? 15 : cy);
    int cz = (int)(z * 16.f); cz = cz < 0 ? 0 : (cz > 15 ? 15 : cz);
    int m = 0;
#pragma unroll
    for (int k = 0; k < 4; ++k)
      m |= (((cx >> k) & 1) << (3*k+2)) | (((cy >> k) & 1) << (3*k+1)) | (((cz >> k) & 1) << (3*k));
    atomicAdd(&hist[m], 1);
  }
  __syncthreads();
  int loc[CPT]; int run = 0;
#pragma unroll
  for (int j = 0; j < CPT; ++j) { loc[j] = run; run += hist[t*CPT + j]; }
  scanbuf[t] = run;
  __syncthreads();
  for (int off = 1; off < NT; off <<= 1) {
    const int o = (t >= off) ? scanbuf[t - off] : 0;
    __syncthreads();
    scanbuf[t] += o;
    __syncthreads();
  }
  const int base = scanbuf[t] - run;
#pragma unroll
  for (int j = 0; j < CPT; ++j) hist[t*CPT + j] = base + loc[j];
  __syncthreads();
  for (int i = t; i < N; i += NT) {
    const float x = sxyz[3*i+0], y = sxyz[3*i+1], z = sxyz[3*i+2];
    int cx = (int)(x * 16.f); cx = cx < 0 ? 0 : (cx > 15 ? 15 : cx);
    int cy = (int)(y * 16.f); cy = cy < 0 ? 0 : (cy > 15 ? 15 : cy);
    int cz = (int)(z * 16.f); cz = cz < 0 ? 0 : (cz > 15 ? 15 : cz);
    int m = 0;
#pragma unroll
    for (int k = 0; k < 4; ++k)
      m |= (((cx >> k) & 1) << (3*k+2)) | (((cy >> k) & 1) << (3*k+1)) | (((cz >> k) & 1) << (3*k));
    const int sl = atomicAdd(&hist[m], 1);
    sorder[sl] = i;
  }
  __syncthreads();
  float px[PPT], py[PPT], pz[PPT], d[PPT];
  int og[PPT];
  float bxmin = POS_INF, bxmax = NEG_INF, bymin = POS_INF, bymax = NEG_INF,
        bzmin = POS_INF, bzmax = NEG_INF;
#pragma unroll
  for (int j = 0; j < PPT; ++j) {
    const int o = sorder[t*PPT + j];
    og[j] = o;
    const float x = sxyz[3*o+0], y = sxyz[3*o+1], z = sxyz[3*o+2];
    px[j] = x; py[j] = y; pz[j] = z;
    bxmin = fminf(bxmin, x); bxmax = fmaxf(bxmax, x);
    bymin = fminf(bymin, y); bymax = fmaxf(bymax, y);
    bzmin = fminf(bzmin, z); bzmax = fmaxf(bzmax, z);
    d[j] = POS_INF;
  }
  __syncthreads();

  const int lane = t & 63;
  float cval = POS_INF;
  int corig = 0x7fffffff;
  int wmvb = 0;
  int wwo = 0x7fffffff;
  int worig = 0;
  int p = 0;

  for (int it = 0; it < S; ++it) {
    if (t == 0) swin[it] = worig;
    const float lx = sxyz[3*worig+0], ly = sxyz[3*worig+1], lz = sxyz[3*worig+2];

    const float ddx = fmaxf(0.f, fmaxf(bxmin - lx, lx - bxmax));
    const float ddy = fmaxf(0.f, fmaxf(bymin - ly, ly - bymax));
    const float ddz = fmaxf(0.f, fmaxf(bzmin - lz, lz - bzmax));
    const float mind2 = ddx*ddx + ddy*ddy + ddz*ddz;
    const bool rec = !(mind2 * 0.99999f >= cval);

    if (rec) {
      float bv = -1.f; int bo = 0x7fffffff;
#pragma unroll
      for (int j = 0; j < PPT; ++j) {
        const float dx = __fsub_rn(px[j], lx);
        const float dy = __fsub_rn(py[j], ly);
        const float dz = __fsub_rn(pz[j], lz);
        const float nd = __fadd_rn(__fadd_rn(__fmul_rn(dx, dx), __fmul_rn(dy, dy)),
                                   __fmul_rn(dz, dz));
        const float dn = __builtin_fminf(d[j], nd);
        d[j] = dn;
        if (dn > bv || (dn == bv && og[j] < bo)) { bv = dn; bo = og[j]; }
      }
      cval = bv; corig = bo;
    }

    if (__ballot(rec) != 0ULL) {
      const int x = __float_as_int(cval);
      int y = x;
      y = dpp_imax_step<0x111, 0xf>(y);
      y = dpp_imax_step<0x112, 0xf>(y);
      y = dpp_imax_step<0x114, 0xf>(y);
      y = dpp_imax_step<0x118, 0xf>(y);
      y = dpp_imax_step<0x142, 0xa>(y);
      y = dpp_imax_step<0x143, 0xc>(y);
      wmvb = __builtin_amdgcn_readlane(y, 63);
      unsigned long long tie = __ballot(__float_as_int(cval) == wmvb);
      int wo = 0x7fffffff;
      while (tie) {
        const int l = __builtin_ctzll(tie);
        const int o = __builtin_amdgcn_readlane(corig, l);
        wo = wo < o ? wo : o;
        tie &= tie - 1;
      }
      wwo = wo;
    }

    if (lane == 0)
      atomicMax(&slot[p], ((unsigned long long)(unsigned)wmvb << 32) |
                          (unsigned)~(unsigned)wwo);
    if (t == 0) slot[(p + 1) & 3] = 0;
    __syncthreads();
    const unsigned long long wm = slot[p];
    worig = (int)(~(unsigned)(wm & 0xffffffffULL));
    p = (p + 1) & 3;
  }

  __syncthreads();
  for (int s = t; s < S; s += NT) {
    const int o = swin[s];
    q_out[3*s+0] = sxyz[3*o+0]; q_out[3*s+1] = sxyz[3*o+1]; q_out[3*s+2] = sxyz[3*o+2];
  }
}

// ============================ combo: fps2 (blocks 0,1)  ||  knn1+mlp1 (blocks 2+) ============================
// SIBLING overlap only: both halves read q1, which is COMPLETE (written by the
// previous kernel) -> kernel-boundary coherence, NO atomics / spins / fences.
// If consumers were not co-resident with fps2 the kernel just runs serially.
struct Prod2S {                // fps2 geometry: N=4096
  unsigned long long slot[4];
  float sxyz[3 * 4096];
  int sorder[4096];
  int hist[4096];
  int scanbuf[1024];
};
struct Cons1S {                // fused knn1+mlp1, one query per block
  unsigned long long keys[2048];
  float sW2[64 * 64];
  float sW3[64 * 128];
  float sW1[3 * 64];
  float sb1[64], sb2[64], sb3[128];
  float h1[64][65];
  float h2b[64][65];
  float featT[3][64];
  int snb[64];
  int s_cnt;
};
constexpr size_t SMC = sizeof(Prod2S) > sizeof(Cons1S) ? sizeof(Prod2S) : sizeof(Cons1S);

__global__ __launch_bounds__(1024)
void combo2_kernel(const float* __restrict__ pos,
                   const float* __restrict__ q1,
                   float* __restrict__ q2,
                   float* __restrict__ x1,
                   const float* __restrict__ W1, const float* __restrict__ b1,
                   const float* __restrict__ W2, const float* __restrict__ b2,
                   const float* __restrict__ W3, const float* __restrict__ b3)
{
  __shared__ __align__(16) char smraw[SMC];
  const int bid = blockIdx.x;
  const int t = threadIdx.x;

  if (bid < 2) {
    // ---------------- fps2: N=4096, PPT=4, S=1024, NT=1024 ----------------
    constexpr int N = 4096, PPT = 4, S = 1024, NT = 1024;
    constexpr int CELLS = 4096, CPT = CELLS / NT;
    Prod2S& P = *reinterpret_cast<Prod2S*>(smraw);
    const float* pb = q1 + (size_t)bid * N * 3;
    float* qb = q2 + (size_t)bid * S * 3;
    int* const swin = P.hist;

    for (int i = t; i < CELLS; i += NT) P.hist[i] = 0;
    if (t < 4) P.slot[t] = 0;
    __syncthreads();
    for (int i = t; i < N; i += NT) {
      const float x = pb[3*i+0], y = pb[3*i+1], z = pb[3*i+2];
      P.sxyz[3*i+0] = x; P.sxyz[3*i+1] = y; P.sxyz[3*i+2] = z;
      int cx = (int)(x * 16.f); cx = cx < 0 ? 0 : (cx > 15 ? 15 : cx);
      int cy = (int)(y * 16.f); cy = cy < 0 ? 0 : (cy > 15 ? 15 : cy);
      int cz = (int)(z * 16.f); cz = cz < 0 ? 0 : (cz > 15 ? 15 : cz);
      int m = 0;
#pragma unroll
      for (int k = 0; k < 4; ++k)
        m |= (((cx >> k) & 1) << (3*k+2)) | (((cy >> k) & 1) << (3*k+1)) | (((cz >> k) & 1) << (3*k));
      atomicAdd(&P.hist[m], 1);
    }
    __syncthreads();
    int loc[CPT]; int run = 0;
#pragma unroll
    for (int j = 0; j < CPT; ++j) { loc[j] = run; run += P.hist[t*CPT + j]; }
    P.scanbuf[t] = run;
    __syncthreads();
    for (int off = 1; off < NT; off <<= 1) {
      const int o = (t >= off) ? P.scanbuf[t - off] : 0;
      __syncthreads();
      P.scanbuf[t] += o;
      __syncthreads();
    }
    const int base = P.scanbuf[t] - run;
#pragma unroll
    for (int j = 0; j < CPT; ++j) P.hist[t*CPT + j] = base + loc[j];
    __syncthreads();
    for (int i = t; i < N; i += NT) {
      const float x = P.sxyz[3*i+0], y = P.sxyz[3*i+1], z = P.sxyz[3*i+2];
      int cx = (int)(x * 16.f); cx = cx < 0 ? 0 : (cx > 15 ? 15 : cx);
      int cy = (int)(y * 16.f); cy = cy < 0 ? 0 : (cy > 15 ? 15 : cy);
      int cz = (int)(z * 16.f); cz = cz < 0 ? 0 : (cz > 15 ? 15 : cz);
      int m = 0;
#pragma unroll
      for (int k = 0; k < 4; ++k)
        m |= (((cx >> k) & 1) << (3*k+2)) | (((cy >> k) & 1) << (3*k+1)) | (((cz >> k) & 1) << (3*k));
      const int sl = atomicAdd(&P.hist[m], 1);
      P.sorder[sl] = i;
    }
    __syncthreads();
    float px[PPT], py[PPT], pz[PPT], d[PPT];
    int og[PPT];
    float bxmin = POS_INF, bxmax = NEG_INF, bymin = POS_INF, bymax = NEG_INF,
          bzmin = POS_INF, bzmax = NEG_INF;
#pragma unroll
    for (int j = 0; j < PPT; ++j) {
      const int o = P.sorder[t*PPT + j];
      og[j] = o;
      const float x = P.sxyz[3*o+0], y = P.sxyz[3*o+1], z = P.sxyz[3*o+2];
      px[j] = x; py[j] = y; pz[j] = z;
      bxmin = fminf(bxmin, x); bxmax = fmaxf(bxmax, x);
      bymin = fminf(bymin, y); bymax = fmaxf(bymax, y);
      bzmin = fminf(bzmin, z); bzmax = fmaxf(bzmax, z);
      d[j] = POS_INF;
    }
    __syncthreads();

    const int lane = t & 63;
    float cval = POS_INF;
    int corig = 0x7fffffff;
    int wmvb = 0;
    int wwo = 0x7fffffff;
    int worig = 0;
    int p = 0;

    for (int it = 0; it < S; ++it) {
      if (t == 0) swin[it] = worig;
      const float lx = P.sxyz[3*worig+0], ly = P.sxyz[3*worig+1], lz = P.sxyz[3*worig+2];

      const float ddx = fmaxf(0.f, fmaxf(bxmin - lx, lx - bxmax));
      const float ddy = fmaxf(0.f, fmaxf(bymin - ly, ly - bymax));
      const float ddz = fmaxf(0.f, fmaxf(bzmin - lz, lz - bzmax));
      const float mind2 = ddx*ddx + ddy*ddy + ddz*ddz;
      const bool rec = !(mind2 * 0.99999f >= cval);

      if (rec) {
        float bv = -1.f; int bo = 0x7fffffff;
#pragma unroll
        for (int j = 0; j < PPT; ++j) {
          const float dx = __fsub_rn(px[j], lx);
          const float dy = __fsub_rn(py[j], ly);
          const float dz = __fsub_rn(pz[j], lz);
          const float nd = __fadd_rn(__fadd_rn(__fmul_rn(dx, dx), __fmul_rn(dy, dy)),
                                     __fmul_rn(dz, dz));
          const float dn = __builtin_fminf(d[j], nd);
          d[j] = dn;
          if (dn > bv || (dn == bv && og[j] < bo)) { bv = dn; bo = og[j]; }
        }
        cval = bv; corig = bo;
      }

      if (__ballot(rec) != 0ULL) {
        const int x = __float_as_int(cval);
        int y = x;
        y = dpp_imax_step<0x111, 0xf>(y);
        y = dpp_imax_step<0x112, 0xf>(y);
        y = dpp_imax_step<0x114, 0xf>(y);
        y = dpp_imax_step<0x118, 0xf>(y);
        y = dpp_imax_step<0x142, 0xa>(y);
        y = dpp_imax_step<0x143, 0xc>(y);
        wmvb = __builtin_amdgcn_readlane(y, 63);
        unsigned long long tie = __ballot(__float_as_int(cval) == wmvb);
        int wo = 0x7fffffff;
        while (tie) {
          const int l = __builtin_ctzll(tie);
          const int o = __builtin_amdgcn_readlane(corig, l);
          wo = wo < o ? wo : o;
          tie &= tie - 1;
        }
        wwo = wo;
      }

      if (lane == 0)
        atomicMax(&P.slot[p], ((unsigned long long)(unsigned)wmvb << 32) |
                              (unsigned)~(unsigned)wwo);
      if (t == 0) P.slot[(p + 1) & 3] = 0;
      __syncthreads();
      const unsigned long long wm = P.slot[p];
      worig = (int)(~(unsigned)(wm & 0xffffffffULL));
      p = (p + 1) & 3;
    }

    __syncthreads();
    for (int s = t; s < S; s += NT) {
      const int o = swin[s];
      qb[3*s+0] = P.sxyz[3*o+0]; qb[3*s+1] = P.sxyz[3*o+1]; qb[3*s+2] = P.sxyz[3*o+2];
    }
    return;
  }

  // ---------------- consumer: fused knn1 + mlp1, one query per block ----------------
  Cons1S& C = *reinterpret_cast<Cons1S*>(smraw);
  const float R1SQ = (float)(0.2 * 0.2);
  const int qi = bid - 2;              // 0..8191
  const int g = qi >> 12;
  const float* cb = pos + (size_t)g * 8192 * 3;
  const float qx = q1[3*qi+0], qy = q1[3*qi+1], qz = q1[3*qi+2];

  // stage SA1 weights
  for (int i = t; i < 192; i += 1024) C.sW1[i] = W1[i];
  if (t < 64) { C.sb1[t] = b1[t]; C.sb2[t] = b2[t]; }
  for (int i = t; i < 4096; i += 1024) C.sW2[i] = W2[i];
  for (int i = t; i < 8192; i += 1024) C.sW3[i] = W3[i];
  if (t < 128) C.sb3[t] = b3[t];
  if (t == 0) C.s_cnt = 0;
  __syncthreads();

  // radius compaction (exact ops)
  for (int i = t; i < 8192; i += 1024) {
    const float dx = __fsub_rn(cb[3*i+0], qx);
    const float dy = __fsub_rn(cb[3*i+1], qy);
    const float dz = __fsub_rn(cb[3*i+2], qz);
    const float d2 = __fadd_rn(__fadd_rn(__fmul_rn(dx, dx), __fmul_rn(dy, dy)),
                               __fmul_rn(dz, dz));
    if (d2 <= R1SQ) {
      const int pp = atomicAdd(&C.s_cnt, 1);
      if (pp < 2048)
        C.keys[pp] = ((unsigned long long)__float_as_uint(d2) << 32) | (unsigned)i;
    }
  }
  __syncthreads();
  const int M = min(C.s_cnt, 2048);
  const int cnt = min(M, 64);
  if (M > 64) {
    int P2 = 128; while (P2 < M) P2 <<= 1;
    for (int i = M + t; i < P2; i += 1024) C.keys[i] = ~0ULL;
    __syncthreads();
    for (int k = 2; k <= P2; k <<= 1) {
      for (int j = k >> 1; j > 0; j >>= 1) {
        for (int i = t; i < P2; i += 1024) {
          const int l = i ^ j;
          if (l > i) {
            const unsigned long long a = C.keys[i], c = C.keys[l];
            const bool up = ((i & k) == 0);
            if ((a > c) == up) { C.keys[i] = c; C.keys[l] = a; }
          }
        }
        __syncthreads();
      }
    }
  }
  if (t < 64) C.snb[t] = (t < cnt) ? (int)(C.keys[t] & 0xffffffffu) : 0;
  __syncthreads();

  // SA1 edge MLP (identical arithmetic to the verified mlp1)
  const int e = t & 63, cg = t >> 6;
  if (t < 64) {
    float r0 = 0.f, r1 = 0.f, r2v = 0.f;
    if (t < cnt) {
      const int nb = C.snb[t];
      r0 = cb[3*nb+0] - qx;
      r1 = cb[3*nb+1] - qy;
      r2v = cb[3*nb+2] - qz;
    }
    C.featT[0][t] = r0; C.featT[1][t] = r1; C.featT[2][t] = r2v;
  }
  __syncthreads();
  { // layer1: 64 cols / 16 groups = 4 cols/thread
    const int c0 = cg * 4;
    const float a0 = C.featT[0][e], a1 = C.featT[1][e], a2 = C.featT[2][e];
#pragma unroll
    for (int i = 0; i < 4; ++i) {
      float v = C.sb1[c0+i];
      v = fmaf(a0, C.sW1[0*64 + c0+i], v);
      v = fmaf(a1, C.sW1[1*64 + c0+i], v);
      v = fmaf(a2, C.sW1[2*64 + c0+i], v);
      C.h1[e][c0+i] = fmaxf(v, 0.f);
    }
  }
  __syncthreads();
  { // layer2: 4 cols/thread
    const int c0 = cg * 4;
    float acc[4];
#pragma unroll
    for (int i = 0; i < 4; ++i) acc[i] = C.sb2[c0+i];
    for (int k = 0; k < 64; ++k) {
      const float a = C.h1[e][k];
      const float4 w = *reinterpret_cast<const float4*>(&C.sW2[k*64 + c0]);
      acc[0] = fmaf(a, w.x, acc[0]);
      acc[1] = fmaf(a, w.y, acc[1]);
      acc[2] = fmaf(a, w.z, acc[2]);
      acc[3] = fmaf(a, w.w, acc[3]);
    }
#pragma unroll
    for (int i = 0; i < 4; ++i) C.h2b[e][c0+i] = fmaxf(acc[i], 0.f);
  }
  __syncthreads();
  float acc3[8];
  const int c0h = cg * 8;
  { // layer3: 8 cols/thread (no relu)
#pragma unroll
    for (int i = 0; i < 8; ++i) acc3[i] = C.sb3[c0h+i];
    for (int k = 0; k < 64; ++k) {
      const float a = C.h2b[e][k];
      const float4* wp = reinterpret_cast<const float4*>(&C.sW3[k*128 + c0h]);
      const float4 w0 = wp[0], w1 = wp[1];
      acc3[0] = fmaf(a, w0.x, acc3[0]);
      acc3[1] = fmaf(a, w0.y, acc3[1]);
      acc3[2] = fmaf(a, w0.z, acc3[2]);
      acc3[3] = fmaf(a, w0.w, acc3[3]);
      acc3[4] = fmaf(a, w1.x, acc3[4]);
      acc3[5] = fmaf(a, w1.y, acc3[5]);
      acc3[6] = fmaf(a, w1.z, acc3[6]);
      acc3[7] = fmaf(a, w1.w, acc3[7]);
    }
  }
  __syncthreads();   // all h1/h2b reads done before restaging
  {
    const bool valid = (e < cnt);
#pragma unroll
    for (int i = 0; i < 8; ++i) {
      const float v = valid ? acc3[i] : NEG_INF;
      const int c = c0h + i;
      if (c < 64) C.h1[e][c] = v; else C.h2b[e][c-64] = v;
    }
  }
  __syncthreads();
  if (t < 128) {
    float m = NEG_INF;
    if (t < 64) {
      for (int ee = 0; ee < 64; ++ee) m = fmaxf(m, C.h1[ee][t]);
    } else {
      for (int ee = 0; ee < 64; ++ee) m = fmaxf(m, C.h2b[ee][t-64]);
    }
    x1[(size_t)qi*128 + t] = m;
  }
}

// ============================ radius-KNN (stage 2) ============================
#define KNN_CAP 2048

__global__ __launch_bounds__(256) void knn_kernel(const float* __restrict__ cand,
                                                  const float* __restrict__ qpos,
                                                  int nq_per_graph, int n_cand, float r2,
                                                  int* __restrict__ nbr_out,
                                                  int* __restrict__ cnt_out)
{
  const int qi = blockIdx.x;
  const int t = threadIdx.x;
  const int b = qi / nq_per_graph;
  const float* cb = cand + (size_t)b * n_cand * 3;
  const float qx = qpos[3*qi+0], qy = qpos[3*qi+1], qz = qpos[3*qi+2];

  __shared__ unsigned long long keys[KNN_CAP];
  __shared__ int s_cnt;
  if (t == 0) s_cnt = 0;
  __syncthreads();

  for (int i = t; i < n_cand; i += 256) {
    const float dx = __fsub_rn(cb[3*i+0], qx);
    const float dy = __fsub_rn(cb[3*i+1], qy);
    const float dz = __fsub_rn(cb[3*i+2], qz);
    const float d2 = __fadd_rn(__fadd_rn(__fmul_rn(dx, dx), __fmul_rn(dy, dy)),
                               __fmul_rn(dz, dz));
    if (d2 <= r2) {
      const int p = atomicAdd(&s_cnt, 1);
      if (p < KNN_CAP) keys[p] = ((unsigned long long)__float_as_uint(d2) << 32) | (unsigned)i;
    }
  }
  __syncthreads();
  const int M = min(s_cnt, KNN_CAP);
  const int out_n = min(M, 64);
  if (M > 64) {
    int P = 128; while (P < M) P <<= 1;
    for (int i = M + t; i < P; i += 256) keys[i] = ~0ULL;
    __syncthreads();
    for (int k = 2; k <= P; k <<= 1) {
      for (int j = k >> 1; j > 0; j >>= 1) {
        for (int i = t; i < P; i += 256) {
          const int l = i ^ j;
          if (l > i) {
            const unsigned long long a = keys[i], c = keys[l];
            const bool up = ((i & k) == 0);
            if ((a > c) == up) { keys[i] = c; keys[l] = a; }
          }
        }
        __syncthreads();
      }
    }
  }
  if (t < 64) nbr_out[(size_t)qi*64 + t] = (t < out_n) ? (int)(keys[t] & 0xffffffffu) : -1;
  if (t == 0) cnt_out[qi] = out_n;
}

// ============================ SA2 edge MLP (131->128->128->256) + max ============================
__global__ __launch_bounds__(256) void mlp2_kernel(const float* __restrict__ q1,
                                                   const float* __restrict__ x1,
                                                   const float* __restrict__ q2,
                                                   const int* __restrict__ nbr,
                                                   const int* __restrict__ cnt_,
                                                   const float* __restrict__ W1, const float* __restrict__ b1,
                                                   const float* __restrict__ W2, const float* __restrict__ b2,
                                                   const float* __restrict__ W3, const float* __restrict__ b3,
                                                   float* __restrict__ x2)
{
  const int qi = blockIdx.x;
  const int t = threadIdx.x;
  const int bg = qi >> 10;
  const float* cb = q1 + (size_t)bg * 4096 * 3;
  const float* xb = x1 + (size_t)bg * 4096 * 128;

  __shared__ float sW[131*128];
  __shared__ float sb[256];
  __shared__ float featT[131][64];
  __shared__ float hbuf[64][129];
  __shared__ int snb[64];

  const int cnt = cnt_[qi];
  const float qx = q2[3*qi+0], qy = q2[3*qi+1], qz = q2[3*qi+2];

  if (t < 64) {
    const int nb = (t < cnt) ? nbr[(size_t)qi*64 + t] : 0;
    snb[t] = nb;
    float r0 = 0.f, r1 = 0.f, r2v = 0.f;
    if (t < cnt) {
      r0 = cb[3*nb+0] - qx;
      r1 = cb[3*nb+1] - qy;
      r2v = cb[3*nb+2] - qz;
    }
    featT[128][t] = r0; featT[129][t] = r1; featT[130][t] = r2v;
  }
  for (int i = t; i < 131*128; i += 256) sW[i] = W1[i];
  if (t < 128) sb[t] = b1[t];
  __syncthreads();
  for (int idx = t; idx < 64*128; idx += 256) {
    const int e = idx >> 7, k = idx & 127;
    featT[k][e] = (e < cnt) ? xb[(size_t)snb[e]*128 + k] : 0.f;
  }
  __syncthreads();

  const int e = t & 63, cg = t >> 6, c0 = cg * 32;
  float acc[32];
  { // layer1: 131 -> 128
#pragma unroll
    for (int i = 0; i < 32; ++i) acc[i] = sb[c0+i];
    for (int k = 0; k < 131; ++k) {
      const float a = featT[k][e];
      const float4* wp = reinterpret_cast<const float4*>(&sW[k*128 + c0]);
#pragma unroll
      for (int i = 0; i < 8; ++i) {
        const float4 w = wp[i];
        acc[4*i+0] = fmaf(a, w.x, acc[4*i+0]);
        acc[4*i+1] = fmaf(a, w.y, acc[4*i+1]);
        acc[4*i+2] = fmaf(a, w.z, acc[4*i+2]);
        acc[4*i+3] = fmaf(a, w.w, acc[4*i+3]);
      }
    }
#pragma unroll
    for (int i = 0; i < 32; ++i) hbuf[e][c0+i] = fmaxf(acc[i], 0.f);
  }
  __syncthreads();
  for (int i = t; i < 128*128; i += 256) sW[i] = W2[i];
  if (t < 128) sb[t] = b2[t];
  __syncthreads();
  { // layer2
#pragma unroll
    for (int i = 0; i < 32; ++i) acc[i] = sb[c0+i];
    for (int k = 0; k < 128; ++k) {
      const float a = hbuf[e][k];
      const float4* wp = reinterpret_cast<const float4*>(&sW[k*128 + c0]);
#pragma unroll
      for (int i = 0; i < 8; ++i) {
        const float4 w = wp[i];
        acc[4*i+0] = fmaf(a, w.x, acc[4*i+0]);
        acc[4*i+1] = fmaf(a, w.y, acc[4*i+1]);
        acc[4*i+2] = fmaf(a, w.z, acc[4*i+2]);
        acc[4*i+3] = fmaf(a, w.w, acc[4*i+3]);
      }
    }
  }
  __syncthreads();
#pragma unroll
  for (int i = 0; i < 32; ++i) featT[c0+i][e] = fmaxf(acc[i], 0.f);
  __syncthreads();
  for (int hh = 0; hh < 2; ++hh) {
    for (int i = t; i < 128*128; i += 256) {
      const int k = i >> 7, c = i & 127;
      sW[i] = W3[k*256 + hh*128 + c];
    }
    if (t < 128) sb[t] = b3[hh*128 + t];
    __syncthreads();
#pragma unroll
    for (int i = 0; i < 32; ++i) acc[i] = sb[c0+i];
    for (int k = 0; k < 128; ++k) {
      const float a = featT[k][e];
      const float4* wp = reinterpret_cast<const float4*>(&sW[k*128 + c0]);
#pragma unroll
      for (int i = 0; i < 8; ++i) {
        const float4 w = wp[i];
        acc[4*i+0] = fmaf(a, w.x, acc[4*i+0]);
        acc[4*i+1] = fmaf(a, w.y, acc[4*i+1]);
        acc[4*i+2] = fmaf(a, w.z, acc[4*i+2]);
        acc[4*i+3] = fmaf(a, w.w, acc[4*i+3]);
      }
    }
    const bool valid = (e < cnt);
#pragma unroll
    for (int i = 0; i < 32; ++i) hbuf[e][c0+i] = valid ? acc[i] : NEG_INF;
    __syncthreads();
    if (t < 128) {
      float m = NEG_INF;
      for (int ee = 0; ee < 64; ++ee) m = fmaxf(m, hbuf[ee][t]);
      x2[(size_t)qi*256 + hh*128 + t] = m;
    }
    __syncthreads();
  }
}

// ============================ head MLP (256->256->128->1, sigmoid) ============================
__global__ __launch_bounds__(256) void head_kernel(const float* __restrict__ x2,
                                                   const float* __restrict__ W1, const float* __restrict__ b1,
                                                   const float* __restrict__ W2, const float* __restrict__ b2,
                                                   const float* __restrict__ W3, const float* __restrict__ b3,
                                                   float* __restrict__ out)
{
  const int pt = blockIdx.x;
  const int t = threadIdx.x;
  __shared__ float sx[256];
  __shared__ float sh1[256];
  __shared__ float sh2[128];
  __shared__ float red[128];

  sx[t] = x2[(size_t)pt*256 + t];
  __syncthreads();
  float a1 = b1[t];
  for (int k = 0; k < 256; ++k) a1 = fmaf(sx[k], W1[k*256 + t], a1);
  sh1[t] = fmaxf(a1, 0.f);
  __syncthreads();
  if (t < 128) {
    float a2 = b2[t];
    for (int k = 0; k < 256; ++k) a2 = fmaf(sh1[k], W2[k*128 + t], a2);
    sh2[t] = fmaxf(a2, 0.f);
  }
  __syncthreads();
  if (t < 128) red[t] = sh2[t] * W3[t];
  __syncthreads();
  for (int o = 64; o > 0; o >>= 1) {
    if (t < o) red[t] += red[t + o];
    __syncthreads();
  }
  if (t == 0) {
    const float v = red[0] + b3[0];
    out[pt] = 1.f / (1.f + expf(-v));
  }
}

// ============================ launcher ============================
extern "C" void kernel_launch(void* const* d_in, const int* in_sizes, int n_in,
                              void* d_out, int out_size, void* d_ws, size_t ws_size,
                              hipStream_t stream)
{
  (void)in_sizes; (void)n_in; (void)out_size; (void)ws_size;
  const float* pos  = (const float*)d_in[0];
  const float* s1W1 = (const float*)d_in[2];  const float* s1b1 = (const float*)d_in[3];
  const float* s1W2 = (const float*)d_in[4];  const float* s1b2 = (const float*)d_in[5];
  const float* s1W3 = (const float*)d_in[6];  const float* s1b3 = (const float*)d_in[7];
  const float* s2W1 = (const float*)d_in[8];  const float* s2b1 = (const float*)d_in[9];
  const float* s2W2 = (const float*)d_in[10]; const float* s2b2 = (const float*)d_in[11];
  const float* s2W3 = (const float*)d_in[12]; const float* s2b3 = (const float*)d_in[13];
  const float* l1W  = (const float*)d_in[14]; const float* l1b  = (const float*)d_in[15];
  const float* l2W  = (const float*)d_in[16]; const float* l2b  = (const float*)d_in[17];
  const float* l3W  = (const float*)d_in[18]; const float* l3b  = (const float*)d_in[19];
  float* out = (float*)d_out;

  char* w = (char*)d_ws;
  size_t off = 0;
  auto alloc = [&](size_t bytes) -> void* {
    void* p = w + off;
    off += (bytes + 255) & ~(size_t)255;
    return p;
  };
  float* q1   = (float*)alloc((size_t)2*4096*3*4);
  float* q2   = (float*)alloc((size_t)2*1024*3*4);
  float* x1   = (float*)alloc((size_t)8192*128*4);
  float* x2   = (float*)alloc((size_t)2048*256*4);
  int*   nbr2 = (int*)alloc((size_t)2048*64*4);
  int*   cnt2 = (int*)alloc((size_t)2048*4);

  const float R2SQ = (float)(0.4 * 0.4);

  // fps1 (measured-best standalone)
  fpsp_kernel<8192, 8, 4096, 1024><<<dim3(2), dim3(1024), 0, stream>>>(pos, q1);
  // sibling overlap: blocks 0,1 = fps2; blocks 2.. = fused knn1+mlp1 (1 query/block)
  combo2_kernel<<<dim3(8194), dim3(1024), 0, stream>>>(pos, q1, q2, x1,
                                                       s1W1, s1b1, s1W2, s1b2, s1W3, s1b3);
  // stage-2 tail
  knn_kernel<<<dim3(2048), dim3(256), 0, stream>>>(q1, q2, 1024, 4096, R2SQ, nbr2, cnt2);
  mlp2_kernel<<<dim3(2048), dim3(256), 0, stream>>>(q1, x1, q2, nbr2, cnt2,
                                                    s2W1, s2b1, s2W2, s2b2, s2W3, s2b3, x2);
  head_kernel<<<dim3(2048), dim3(256), 0, stream>>>(x2, l1W, l1b, l2W, l2b, l3W, l3b, out);
}